// Round 16
// baseline (110.630 us; speedup 1.0000x reference)
//
#include <hip/hip_runtime.h>
#include <math.h>

#define N_NODES 131072
#define G_GRP   512
#define TPB     256          // 4 waves; wave handles 16 nodes
#define NPB     64           // nodes per block
#define SPAN    32

// ws float offsets
#define ACC_OFF    0         // 3072 floats (512 groups * 6)
#define WB_OFF_F   4096      // 38400 ushort (bf16 weight frags) = 19200 floats
#define CB_OFF_F   23552     // 96 floats (bg2*wpost combos)
#define BG1_OFF_F  23680     // 64 floats

// frag index bases (each frag = 64 lanes x 8 bf16 = 512 ushort)
#define FG1 0    // gate : 16 frags, t*4+kk   (K=128, Ntiles=4)
#define FG2 16   // coef : 12 frags, g*2+kk   (K=64,  Ntiles=6)
#define FG3 28   // s    : 4  frags, kk       (K=128, Ntiles=1)
#define FG4 32   // v    : 18 frags, i*6+kk   (K=192 blockdiag, Ntiles=3)
#define FG5 50   // t    : 25 frags, m*5+kk   (K=160 blockdiag, Ntiles=5)

typedef __attribute__((ext_vector_type(8))) short short8;
typedef __attribute__((ext_vector_type(4))) float f32x4;

__device__ __forceinline__ unsigned short f2bf(float f) {
  union { float f; unsigned u; } v; v.f = f;
  unsigned r = v.u + 0x7FFFu + ((v.u >> 16) & 1u);   // RNE
  return (unsigned short)(r >> 16);
}

__global__ __launch_bounds__(256) void repack_kernel(
    const float* __restrict__ W0, const float* __restrict__ W1,
    const float* __restrict__ W2, const float* __restrict__ Wg1,
    const float* __restrict__ bg1, const float* __restrict__ Wg2,
    const float* __restrict__ bg2, const float* __restrict__ wp0,
    const float* __restrict__ wp2, float* __restrict__ ws)
{
  int i = blockIdx.x * 256 + threadIdx.x;
  if (i < 3072) ws[ACC_OFF + i] = 0.f;               // zero group accumulator
  unsigned short* WB = (unsigned short*)(ws + WB_OFF_F);
  if (i < 38400) {
    int fidx = i >> 9;
    int le = i & 511, l = le >> 3, j = le & 7;
    int lo = l & 15, hi = l >> 4;
    float val = 0.f;
    if (fidx < 16) {                       // gate: B[k][t*16+lo] = Wg1[k][col]
      int t = fidx >> 2, kk = fidx & 3;
      int k = kk * 32 + hi * 8 + j;
      val = Wg1[k * 64 + t * 16 + lo];
    } else if (fidx < 28) {                // coef: wpost-folded Wg2
      int f = fidx - 16, g = f >> 1, kk = f & 1;
      int k = kk * 32 + hi * 8 + j;
      const float* row = Wg2 + k * 144;
      int h = lo;
      switch (g) {
        case 0:  val = wp0[0] * row[h];        break;
        case 1:  val = wp0[1] * row[32 + h];   break;
        case 2:  val = wp0[2] * row[96 + h];   break;
        case 3:  val = wp2[0] * row[16 + h] + wp2[2] * row[80 + h]; break;
        case 4:  val = wp2[1] * row[64 + h];   break;
        default: val = wp2[3] * row[128 + h];  break;
      }
    } else if (fidx < 32) {                // s: W0[k][lo]
      int kk = fidx - 28;
      int k = kk * 32 + hi * 8 + j;
      val = W0[k * 16 + lo];
    } else if (fidx < 50) {                // v blockdiag: k=u*3+ic, col=i*16+h
      int f = fidx - 32, ic = f / 6, kk = f % 6;
      int k = kk * 32 + hi * 8 + j;
      int u = k / 3, cc = k - u * 3;
      val = (cc == ic) ? W1[u * 16 + lo] : 0.f;
    } else {                               // t blockdiag: k=u*5+mc, col=m*16+h
      int f = fidx - 50, mt = f / 5, kk = f % 5;
      int k = kk * 32 + hi * 8 + j;
      int u = k / 5, mc = k - u * 5;
      val = (mc == mt) ? W2[u * 16 + lo] : 0.f;
    }
    WB[i] = f2bf(val);
  } else if (i < 38496) {                  // CB (fp32)
    int o = i - 38400, g = o >> 4, h = o & 15;
    float v;
    switch (g) {
      case 0:  v = wp0[0] * bg2[h];        break;
      case 1:  v = wp0[1] * bg2[32 + h];   break;
      case 2:  v = wp0[2] * bg2[96 + h];   break;
      case 3:  v = wp2[0] * bg2[16 + h] + wp2[2] * bg2[80 + h]; break;
      case 4:  v = wp2[1] * bg2[64 + h];   break;
      default: v = wp2[3] * bg2[128 + h];  break;
    }
    ws[CB_OFF_F + o] = v;
  } else if (i < 38560) {
    ws[BG1_OFF_F + (i - 38496)] = bg1[i - 38496];
  }
}

// ---- templated staging (compile-time F4N/stride: no runtime idiv) ----
template <int F4N>
__device__ __forceinline__ void ld_tile(const float* __restrict__ src, int srcStride,
                                        int baseRow, int tid, float4* __restrict__ buf)
{
#pragma unroll
  for (int it = 0; it < (64 * F4N) / TPB; ++it) {
    int idx = it * TPB + tid;
    int row = idx / F4N, c4 = idx - row * F4N;
    buf[it] = *(const float4*)(src + (size_t)(baseRow + row) * srcStride + c4 * 4);
  }
}
template <int F4N, int LDSS>
__device__ __forceinline__ void st_tile(unsigned short* __restrict__ XS, int tid,
                                        const float4* __restrict__ buf)
{
#pragma unroll
  for (int it = 0; it < (64 * F4N) / TPB; ++it) {
    int idx = it * TPB + tid;
    int row = idx / F4N, c4 = idx - row * F4N;
    uint2 pk;
    pk.x = (unsigned)f2bf(buf[it].x) | ((unsigned)f2bf(buf[it].y) << 16);
    pk.y = (unsigned)f2bf(buf[it].z) | ((unsigned)f2bf(buf[it].w) << 16);
    *(uint2*)(&XS[row * LDSS + c4 * 4]) = pk;
  }
}
template <int F4N, int LDSS>
__device__ __forceinline__ void stage_sync(const float* __restrict__ src, int srcStride,
                                           int baseRow, int tid,
                                           unsigned short* __restrict__ XS)
{
#pragma unroll 2
  for (int it = 0; it < (64 * F4N) / TPB; ++it) {
    int idx = it * TPB + tid;
    int row = idx / F4N, c4 = idx - row * F4N;
    float4 v = *(const float4*)(src + (size_t)(baseRow + row) * srcStride + c4 * 4);
    uint2 pk;
    pk.x = (unsigned)f2bf(v.x) | ((unsigned)f2bf(v.y) << 16);
    pk.y = (unsigned)f2bf(v.z) | ((unsigned)f2bf(v.w) << 16);
    *(uint2*)(&XS[row * LDSS + c4 * 4]) = pk;
  }
}

__global__ __launch_bounds__(TPB, 4) void node_kernel(
    const float* __restrict__ xsc, const float* __restrict__ xsp,
    const int* __restrict__ bidx, float* __restrict__ ws)
{
  __shared__ unsigned short XS[64 * 200];      // padded x tile (reused per phase)
  __shared__ unsigned short HB[4 * 16 * 72];   // per-wave silu(H) bf16, stride 72
  __shared__ float accL[SPAN * 6];
  const int tid = threadIdx.x;
  const int w = tid >> 6, l = tid & 63;
  const int lo = l & 15, hi = l >> 4;
  const int blk = blockIdx.x;
  const int baseRow = blk * 64;
  const unsigned short* __restrict__ WB = (const unsigned short*)(ws + WB_OFF_F);

  for (int i = tid; i < SPAN * 6; i += TPB) accL[i] = 0.f;

  const float SQ2 = 1.41421356237f;
  const float I2  = 0.70710678118f;
  const float I6  = 0.40824829046f;

  auto afrag = [&](int kk, int ldsStride) -> short8 {
    return *(const short8*)(&XS[(w * 16 + lo) * ldsStride + kk * 32 + hi * 8]);
  };
  auto bfrag = [&](int fidx) -> short8 {
    return *(const short8*)(WB + (fidx << 9) + (l << 3));
  };

  // stage gate tile (synchronous)
  stage_sync<32, 136>(xsc, 128, baseRow, tid, XS);
  __syncthreads();

  // prefetch s tile while G1/G2 compute (T14: issue-early / write-late)
  float4 bufS[8];
  ld_tile<32>(xsp, 480, baseRow, tid, bufS);

  // ---------- G1: gate H[16x64] ----------
  f32x4 hacc[4];
  {
    short8 a0 = afrag(0,136), a1 = afrag(1,136), a2 = afrag(2,136), a3 = afrag(3,136);
#pragma unroll
    for (int t = 0; t < 4; ++t) {
      f32x4 acc = {0.f, 0.f, 0.f, 0.f};
      acc = __builtin_amdgcn_mfma_f32_16x16x32_bf16(a0, bfrag(FG1 + t*4 + 0), acc, 0, 0, 0);
      acc = __builtin_amdgcn_mfma_f32_16x16x32_bf16(a1, bfrag(FG1 + t*4 + 1), acc, 0, 0, 0);
      acc = __builtin_amdgcn_mfma_f32_16x16x32_bf16(a2, bfrag(FG1 + t*4 + 2), acc, 0, 0, 0);
      acc = __builtin_amdgcn_mfma_f32_16x16x32_bf16(a3, bfrag(FG1 + t*4 + 3), acc, 0, 0, 0);
      hacc[t] = acc;
    }
  }
  // silu + bias -> HB (bf16), C-layout row = hi*4+r, col = t*16+lo
  {
    const float* __restrict__ BG1f = ws + BG1_OFF_F;
    unsigned short* __restrict__ hb = &HB[w * 16 * 72];
#pragma unroll
    for (int t = 0; t < 4; ++t) {
      float bb = BG1f[t * 16 + lo];
#pragma unroll
      for (int r = 0; r < 4; ++r) {
        float hv = hacc[t][r] + bb;
        float sg = hv / (1.f + __expf(-hv));
        hb[(hi * 4 + r) * 72 + t * 16 + lo] = f2bf(sg);
      }
    }
  }
  // ---------- G2: coef C[16x96] (A from HB, same wave -> no barrier) ----------
  f32x4 cacc[6];
  {
    const unsigned short* __restrict__ hb = &HB[w * 16 * 72];
    short8 a0 = *(const short8*)(&hb[lo * 72 + hi * 8]);
    short8 a1 = *(const short8*)(&hb[lo * 72 + 32 + hi * 8]);
#pragma unroll
    for (int g = 0; g < 6; ++g) {
      f32x4 acc = {0.f, 0.f, 0.f, 0.f};
      acc = __builtin_amdgcn_mfma_f32_16x16x32_bf16(a0, bfrag(FG2 + g*2 + 0), acc, 0, 0, 0);
      acc = __builtin_amdgcn_mfma_f32_16x16x32_bf16(a1, bfrag(FG2 + g*2 + 1), acc, 0, 0, 0);
      float cb = ws[CB_OFF_F + g * 16 + lo];
      acc[0] += cb; acc[1] += cb; acc[2] += cb; acc[3] += cb;
      cacc[g] = acc;
    }
  }

  __syncthreads();                 // all waves done reading XS (gate)
  st_tile<32, 136>(XS, tid, bufS); // write-late
  __syncthreads();

  // prefetch v tile while G3 computes
  float4 bufV[12];
  ld_tile<48>(xsp + 128, 480, baseRow, tid, bufV);

  // ---------- G3: s[16x16] ----------
  f32x4 sacc = {0.f, 0.f, 0.f, 0.f};
  {
    short8 a0 = afrag(0,136), a1 = afrag(1,136), a2 = afrag(2,136), a3 = afrag(3,136);
    sacc = __builtin_amdgcn_mfma_f32_16x16x32_bf16(a0, bfrag(FG3 + 0), sacc, 0, 0, 0);
    sacc = __builtin_amdgcn_mfma_f32_16x16x32_bf16(a1, bfrag(FG3 + 1), sacc, 0, 0, 0);
    sacc = __builtin_amdgcn_mfma_f32_16x16x32_bf16(a2, bfrag(FG3 + 2), sacc, 0, 0, 0);
    sacc = __builtin_amdgcn_mfma_f32_16x16x32_bf16(a3, bfrag(FG3 + 3), sacc, 0, 0, 0);
  }
  f32x4 P0 = {0,0,0,0};
#pragma unroll
  for (int r = 0; r < 4; ++r) {
    float s = sacc[r];
    P0[r] = fmaf(cacc[0][r] * s, s, P0[r]);   // c0*s^2
    cacc[3][r] *= s;                          // c3 -> c3*s
  }

  __syncthreads();                 // all waves done reading XS (s)
  st_tile<48, 200>(XS, tid, bufV);
  __syncthreads();

  // prefetch t tile while G4 computes; bufV dead above, G4 uses lazy frag
  // loads (no a[6] preload) so peak live stays under the 128-VGPR budget.
  float4 bufT[10];
  ld_tile<40>(xsp + 320, 480, baseRow, tid, bufT);

  // ---------- G4: v[16x48] (3 tiles = components i), lazy A-frags ----------
  f32x4 vacc[3];
  {
#pragma unroll
    for (int i = 0; i < 3; ++i) {
      f32x4 acc = {0.f, 0.f, 0.f, 0.f};
#pragma unroll
      for (int kk = 0; kk < 6; ++kk)
        acc = __builtin_amdgcn_mfma_f32_16x16x32_bf16(afrag(kk, 200), bfrag(FG4 + i*6 + kk), acc, 0, 0, 0);
      vacc[i] = acc;
    }
  }
  f32x4 Q0 = {0,0,0,0}, Q1 = {0,0,0,0}, Q2 = {0,0,0,0}, Q3 = {0,0,0,0}, Q4 = {0,0,0,0};
#pragma unroll
  for (int r = 0; r < 4; ++r) {
    float a = vacc[0][r], b = vacc[1][r], d = vacc[2][r];
    float nv = fmaf(a, a, fmaf(b, b, d * d));
    P0[r] = fmaf(cacc[1][r], nv, P0[r]);                     // c1*|v|^2
    float c4h = cacc[4][r];
    Q0[r] = fmaf(c4h, SQ2 * d * a, Q0[r]);
    Q1[r] = fmaf(c4h, SQ2 * a * b, Q1[r]);
    Q2[r] = fmaf(c4h, (2.f*b*b - d*d - a*a) * I6, Q2[r]);
    Q3[r] = fmaf(c4h, SQ2 * b * d, Q3[r]);
    Q4[r] = fmaf(c4h, (d*d - a*a) * I2, Q4[r]);
  }

  __syncthreads();                 // all waves done reading XS (v)
  st_tile<40, 168>(XS, tid, bufT); // write-late (bufT dies here)
  __syncthreads();

  // ---------- G5: t5[16x80] (5 tiles = components m) ----------
  f32x4 tacc[5];
  {
    short8 a[5];
#pragma unroll
    for (int kk = 0; kk < 5; ++kk) a[kk] = afrag(kk, 168);
#pragma unroll
    for (int m = 0; m < 5; ++m) {
      f32x4 acc = {0.f, 0.f, 0.f, 0.f};
#pragma unroll
      for (int kk = 0; kk < 5; ++kk)
        acc = __builtin_amdgcn_mfma_f32_16x16x32_bf16(a[kk], bfrag(FG5 + m*5 + kk), acc, 0, 0, 0);
      tacc[m] = acc;
    }
  }
#pragma unroll
  for (int r = 0; r < 4; ++r) {
    float q0 = tacc[0][r], q1 = tacc[1][r], q2 = tacc[2][r], q3 = tacc[3][r], q4 = tacc[4][r];
    float nt = fmaf(q0,q0, fmaf(q1,q1, fmaf(q2,q2, fmaf(q3,q3, q4*q4))));
    P0[r] = fmaf(cacc[2][r], nt, P0[r]);                     // c2*|t|^2
    float c3s = cacc[3][r];
    Q0[r] = fmaf(c3s, q0, Q0[r]);
    Q1[r] = fmaf(c3s, q1, Q1[r]);
    Q2[r] = fmaf(c3s, q2, Q2[r]);
    Q3[r] = fmaf(c3s, q3, Q3[r]);
    Q4[r] = fmaf(c3s, q4, Q4[r]);
    float d0 = -q2*I6 - q4*I2;
    float d1 =  2.f*q2*I6;
    float d2 = -q2*I6 + q4*I2;
    float a = q1*I2, b = q0*I2, cc = q3*I2;
    float A00 = fmaf(d0,d0, fmaf(a,a, b*b));
    float A11 = fmaf(a,a, fmaf(d1,d1, cc*cc));
    float A22 = fmaf(b,b, fmaf(cc,cc, d2*d2));
    float A01 = fmaf(a, d0 + d1, b*cc);
    float A02 = fmaf(b, d0 + d2, a*cc);
    float A12 = fmaf(cc, d1 + d2, a*b);
    float c5h = cacc[5][r];
    Q0[r] = fmaf(c5h, SQ2 * A02, Q0[r]);
    Q1[r] = fmaf(c5h, SQ2 * A01, Q1[r]);
    Q2[r] = fmaf(c5h, (2.f*A11 - A22 - A00) * I6, Q2[r]);
    Q3[r] = fmaf(c5h, SQ2 * A12, Q3[r]);
    Q4[r] = fmaf(c5h, (A22 - A00) * I2, Q4[r]);
  }

  // ---------- reduce over 16 h-lanes, segment accumulate ----------
  float* __restrict__ ACC = ws + ACC_OFF;
  int gmin = bidx[blk * 64];
#pragma unroll
  for (int r = 0; r < 4; ++r) {
    float z0 = P0[r], z1 = Q0[r], z2 = Q1[r], z3 = Q2[r], z4 = Q3[r], z5 = Q4[r];
#pragma unroll
    for (int d = 1; d < 16; d <<= 1) {
      z0 += __shfl_xor(z0, d); z1 += __shfl_xor(z1, d); z2 += __shfl_xor(z2, d);
      z3 += __shfl_xor(z3, d); z4 += __shfl_xor(z4, d); z5 += __shfl_xor(z5, d);
    }
    if (lo == 0) {
      int node = blk * 64 + w * 16 + hi * 4 + r;
      int g = bidx[node];
      int rel = g - gmin;
      if (rel < SPAN) {
        atomicAdd(&accL[rel*6 + 0], z0); atomicAdd(&accL[rel*6 + 1], z1);
        atomicAdd(&accL[rel*6 + 2], z2); atomicAdd(&accL[rel*6 + 3], z3);
        atomicAdd(&accL[rel*6 + 4], z4); atomicAdd(&accL[rel*6 + 5], z5);
      } else {
        atomicAdd(&ACC[g*6 + 0], z0); atomicAdd(&ACC[g*6 + 1], z1);
        atomicAdd(&ACC[g*6 + 2], z2); atomicAdd(&ACC[g*6 + 3], z3);
        atomicAdd(&ACC[g*6 + 4], z4); atomicAdd(&ACC[g*6 + 5], z5);
      }
    }
  }
  __syncthreads();
  for (int i = tid; i < SPAN * 6; i += TPB) {
    float val = accL[i];
    if (val != 0.f) atomicAdd(&ACC[gmin * 6 + i], val);
  }
}

__global__ __launch_bounds__(64) void finalize_kernel(
    const float* __restrict__ ws, float* __restrict__ out)
{
  int g = blockIdx.x * 64 + threadIdx.x;
  if (g >= G_GRP) return;
  const float I2 = 0.70710678118f, I3 = 0.57735026919f, I6 = 0.40824829046f;
  const float* A = ws + ACC_OFF + g * 6;
  float g0 = A[0], q0 = A[1], q1 = A[2], q2 = A[3], q3 = A[4], q4 = A[5];
  float M00 = g0*I3 - q2*I6 - q4*I2;
  float M11 = g0*I3 + 2.f*q2*I6;
  float M22 = g0*I3 - q2*I6 + q4*I2;
  float M01 = q1*I2, M02 = q0*I2, M12 = q3*I2;
  float* o = out + g * 9;
  o[0] = M22; o[1] = M02; o[2] = M12;
  o[3] = M02; o[4] = M00; o[5] = M01;
  o[6] = M12; o[7] = M01; o[8] = M11;
}

extern "C" void kernel_launch(void* const* d_in, const int* in_sizes, int n_in,
                              void* d_out, int out_size, void* d_ws, size_t ws_size,
                              hipStream_t stream)
{
  const float* xsc = (const float*)d_in[0];
  const float* xsp = (const float*)d_in[1];
  const int*   bidx = (const int*)d_in[3];
  const float* W0  = (const float*)d_in[4];
  const float* W1  = (const float*)d_in[5];
  const float* W2  = (const float*)d_in[6];
  const float* Wg1 = (const float*)d_in[7];
  const float* bg1 = (const float*)d_in[8];
  const float* Wg2 = (const float*)d_in[9];
  const float* bg2 = (const float*)d_in[10];
  const float* wp0 = (const float*)d_in[11];
  const float* wp2 = (const float*)d_in[12];
  float* ws = (float*)d_ws;

  repack_kernel<<<151, 256, 0, stream>>>(W0, W1, W2, Wg1, bg1, Wg2, bg2, wp0, wp2, ws);
  node_kernel<<<N_NODES / NPB, TPB, 0, stream>>>(xsc, xsp, bidx, ws);
  finalize_kernel<<<(G_GRP + 63) / 64, 64, 0, stream>>>(ws, (float*)d_out);
}

// Round 17
// 79.777 us; speedup vs baseline: 1.3867x; 1.3867x over previous
//
#include <hip/hip_runtime.h>
#include <math.h>

#define N_NODES 131072
#define G_GRP   512
#define TPB     256          // 4 waves; wave handles 16 nodes
#define NPB     64           // nodes per block
#define SPAN    32

// ws float offsets
#define ACC_OFF    0         // 3072 floats (512 groups * 6)
#define WB_OFF_F   4096      // 38400 ushort (bf16 weight frags) = 19200 floats
#define CB_OFF_F   23552     // 96 floats (bg2*wpost combos)
#define BG1_OFF_F  23680     // 64 floats

// frag index bases (each frag = 64 lanes x 8 bf16 = 512 ushort)
#define FG1 0    // gate : 16 frags, t*4+kk   (K=128, Ntiles=4)
#define FG2 16   // coef : 12 frags, g*2+kk   (K=64,  Ntiles=6)
#define FG3 28   // s    : 4  frags, kk       (K=128, Ntiles=1)
#define FG4 32   // v    : 18 frags, i*6+kk   (K=192 blockdiag, Ntiles=3)
#define FG5 50   // t    : 25 frags, m*5+kk   (K=160 blockdiag, Ntiles=5)

typedef __attribute__((ext_vector_type(8))) short short8;
typedef __attribute__((ext_vector_type(4))) float f32x4;

__device__ __forceinline__ unsigned short f2bf(float f) {
  union { float f; unsigned u; } v; v.f = f;
  unsigned r = v.u + 0x7FFFu + ((v.u >> 16) & 1u);   // RNE
  return (unsigned short)(r >> 16);
}

__global__ __launch_bounds__(256) void repack_kernel(
    const float* __restrict__ W0, const float* __restrict__ W1,
    const float* __restrict__ W2, const float* __restrict__ Wg1,
    const float* __restrict__ bg1, const float* __restrict__ Wg2,
    const float* __restrict__ bg2, const float* __restrict__ wp0,
    const float* __restrict__ wp2, float* __restrict__ ws)
{
  int i = blockIdx.x * 256 + threadIdx.x;
  if (i < 3072) ws[ACC_OFF + i] = 0.f;               // zero group accumulator
  unsigned short* WB = (unsigned short*)(ws + WB_OFF_F);
  if (i < 38400) {
    int fidx = i >> 9;
    int le = i & 511, l = le >> 3, j = le & 7;
    int lo = l & 15, hi = l >> 4;
    float val = 0.f;
    if (fidx < 16) {                       // gate: B[k][t*16+lo] = Wg1[k][col]
      int t = fidx >> 2, kk = fidx & 3;
      int k = kk * 32 + hi * 8 + j;
      val = Wg1[k * 64 + t * 16 + lo];
    } else if (fidx < 28) {                // coef: wpost-folded Wg2
      int f = fidx - 16, g = f >> 1, kk = f & 1;
      int k = kk * 32 + hi * 8 + j;
      const float* row = Wg2 + k * 144;
      int h = lo;
      switch (g) {
        case 0:  val = wp0[0] * row[h];        break;
        case 1:  val = wp0[1] * row[32 + h];   break;
        case 2:  val = wp0[2] * row[96 + h];   break;
        case 3:  val = wp2[0] * row[16 + h] + wp2[2] * row[80 + h]; break;
        case 4:  val = wp2[1] * row[64 + h];   break;
        default: val = wp2[3] * row[128 + h];  break;
      }
    } else if (fidx < 32) {                // s: W0[k][lo]
      int kk = fidx - 28;
      int k = kk * 32 + hi * 8 + j;
      val = W0[k * 16 + lo];
    } else if (fidx < 50) {                // v blockdiag: k=u*3+ic, col=i*16+h
      int f = fidx - 32, ic = f / 6, kk = f % 6;
      int k = kk * 32 + hi * 8 + j;
      int u = k / 3, cc = k - u * 3;
      val = (cc == ic) ? W1[u * 16 + lo] : 0.f;
    } else {                               // t blockdiag: k=u*5+mc, col=m*16+h
      int f = fidx - 50, mt = f / 5, kk = f % 5;
      int k = kk * 32 + hi * 8 + j;
      int u = k / 5, mc = k - u * 5;
      val = (mc == mt) ? W2[u * 16 + lo] : 0.f;
    }
    WB[i] = f2bf(val);
  } else if (i < 38496) {                  // CB (fp32)
    int o = i - 38400, g = o >> 4, h = o & 15;
    float v;
    switch (g) {
      case 0:  v = wp0[0] * bg2[h];        break;
      case 1:  v = wp0[1] * bg2[32 + h];   break;
      case 2:  v = wp0[2] * bg2[96 + h];   break;
      case 3:  v = wp2[0] * bg2[16 + h] + wp2[2] * bg2[80 + h]; break;
      case 4:  v = wp2[1] * bg2[64 + h];   break;
      default: v = wp2[3] * bg2[128 + h];  break;
    }
    ws[CB_OFF_F + o] = v;
  } else if (i < 38560) {
    ws[BG1_OFF_F + (i - 38496)] = bg1[i - 38496];
  }
}

// ---- templated staging (compile-time F4N/stride: no runtime idiv) ----
template <int F4N>
__device__ __forceinline__ void ld_tile(const float* __restrict__ src, int srcStride,
                                        int baseRow, int tid, float4* __restrict__ buf)
{
#pragma unroll
  for (int it = 0; it < (64 * F4N) / TPB; ++it) {
    int idx = it * TPB + tid;
    int row = idx / F4N, c4 = idx - row * F4N;
    buf[it] = *(const float4*)(src + (size_t)(baseRow + row) * srcStride + c4 * 4);
  }
}
template <int F4N, int LDSS>
__device__ __forceinline__ void st_tile(unsigned short* __restrict__ XS, int tid,
                                        const float4* __restrict__ buf)
{
#pragma unroll
  for (int it = 0; it < (64 * F4N) / TPB; ++it) {
    int idx = it * TPB + tid;
    int row = idx / F4N, c4 = idx - row * F4N;
    uint2 pk;
    pk.x = (unsigned)f2bf(buf[it].x) | ((unsigned)f2bf(buf[it].y) << 16);
    pk.y = (unsigned)f2bf(buf[it].z) | ((unsigned)f2bf(buf[it].w) << 16);
    *(uint2*)(&XS[row * LDSS + c4 * 4]) = pk;
  }
}
template <int F4N, int LDSS>
__device__ __forceinline__ void stage_sync(const float* __restrict__ src, int srcStride,
                                           int baseRow, int tid,
                                           unsigned short* __restrict__ XS)
{
#pragma unroll 2
  for (int it = 0; it < (64 * F4N) / TPB; ++it) {
    int idx = it * TPB + tid;
    int row = idx / F4N, c4 = idx - row * F4N;
    float4 v = *(const float4*)(src + (size_t)(baseRow + row) * srcStride + c4 * 4);
    uint2 pk;
    pk.x = (unsigned)f2bf(v.x) | ((unsigned)f2bf(v.y) << 16);
    pk.y = (unsigned)f2bf(v.z) | ((unsigned)f2bf(v.w) << 16);
    *(uint2*)(&XS[row * LDSS + c4 * 4]) = pk;
  }
}

__global__ __launch_bounds__(TPB, 4) void node_kernel(
    const float* __restrict__ xsc, const float* __restrict__ xsp,
    const int* __restrict__ bidx, float* __restrict__ ws)
{
  __shared__ unsigned short XS[64 * 200];      // padded x tile (reused per phase)
  __shared__ unsigned short HB[4 * 16 * 72];   // per-wave silu(H) bf16, stride 72
  __shared__ float accL[SPAN * 6];
  const int tid = threadIdx.x;
  const int w = tid >> 6, l = tid & 63;
  const int lo = l & 15, hi = l >> 4;
  const int blk = blockIdx.x;
  const int baseRow = blk * 64;
  const unsigned short* __restrict__ WB = (const unsigned short*)(ws + WB_OFF_F);

  for (int i = tid; i < SPAN * 6; i += TPB) accL[i] = 0.f;

  const float SQ2 = 1.41421356237f;
  const float I2  = 0.70710678118f;
  const float I6  = 0.40824829046f;

  auto afrag = [&](int kk, int ldsStride) -> short8 {
    return *(const short8*)(&XS[(w * 16 + lo) * ldsStride + kk * 32 + hi * 8]);
  };
  auto bfrag = [&](int fidx) -> short8 {
    return *(const short8*)(WB + (fidx << 9) + (l << 3));
  };

  // stage gate tile (synchronous)
  stage_sync<32, 136>(xsc, 128, baseRow, tid, XS);
  __syncthreads();

  // prefetch s tile while G1/G2 compute (T14: issue-early / write-late)
  float4 bufS[8];
  ld_tile<32>(xsp, 480, baseRow, tid, bufS);

  // ---------- G1: gate H[16x64] ----------
  f32x4 hacc[4];
  {
    short8 a0 = afrag(0,136), a1 = afrag(1,136), a2 = afrag(2,136), a3 = afrag(3,136);
#pragma unroll
    for (int t = 0; t < 4; ++t) {
      f32x4 acc = {0.f, 0.f, 0.f, 0.f};
      acc = __builtin_amdgcn_mfma_f32_16x16x32_bf16(a0, bfrag(FG1 + t*4 + 0), acc, 0, 0, 0);
      acc = __builtin_amdgcn_mfma_f32_16x16x32_bf16(a1, bfrag(FG1 + t*4 + 1), acc, 0, 0, 0);
      acc = __builtin_amdgcn_mfma_f32_16x16x32_bf16(a2, bfrag(FG1 + t*4 + 2), acc, 0, 0, 0);
      acc = __builtin_amdgcn_mfma_f32_16x16x32_bf16(a3, bfrag(FG1 + t*4 + 3), acc, 0, 0, 0);
      hacc[t] = acc;
    }
  }
  // silu + bias -> HB (bf16), C-layout row = hi*4+r, col = t*16+lo
  {
    const float* __restrict__ BG1f = ws + BG1_OFF_F;
    unsigned short* __restrict__ hb = &HB[w * 16 * 72];
#pragma unroll
    for (int t = 0; t < 4; ++t) {
      float bb = BG1f[t * 16 + lo];
#pragma unroll
      for (int r = 0; r < 4; ++r) {
        float hv = hacc[t][r] + bb;
        float sg = hv / (1.f + __expf(-hv));
        hb[(hi * 4 + r) * 72 + t * 16 + lo] = f2bf(sg);
      }
    }
  }
  // ---------- G2: coef C[16x96] (A from HB, same wave -> no barrier) ----------
  f32x4 cacc[6];
  {
    const unsigned short* __restrict__ hb = &HB[w * 16 * 72];
    short8 a0 = *(const short8*)(&hb[lo * 72 + hi * 8]);
    short8 a1 = *(const short8*)(&hb[lo * 72 + 32 + hi * 8]);
#pragma unroll
    for (int g = 0; g < 6; ++g) {
      f32x4 acc = {0.f, 0.f, 0.f, 0.f};
      acc = __builtin_amdgcn_mfma_f32_16x16x32_bf16(a0, bfrag(FG2 + g*2 + 0), acc, 0, 0, 0);
      acc = __builtin_amdgcn_mfma_f32_16x16x32_bf16(a1, bfrag(FG2 + g*2 + 1), acc, 0, 0, 0);
      float cb = ws[CB_OFF_F + g * 16 + lo];
      acc[0] += cb; acc[1] += cb; acc[2] += cb; acc[3] += cb;
      cacc[g] = acc;
    }
  }

  __syncthreads();                 // all waves done reading XS (gate)
  st_tile<32, 136>(XS, tid, bufS); // write-late
  __syncthreads();

  // prefetch v tile while G3 computes
  float4 bufV[12];
  ld_tile<48>(xsp + 128, 480, baseRow, tid, bufV);

  // ---------- G3: s[16x16] ----------
  f32x4 sacc = {0.f, 0.f, 0.f, 0.f};
  {
    short8 a0 = afrag(0,136), a1 = afrag(1,136), a2 = afrag(2,136), a3 = afrag(3,136);
    sacc = __builtin_amdgcn_mfma_f32_16x16x32_bf16(a0, bfrag(FG3 + 0), sacc, 0, 0, 0);
    sacc = __builtin_amdgcn_mfma_f32_16x16x32_bf16(a1, bfrag(FG3 + 1), sacc, 0, 0, 0);
    sacc = __builtin_amdgcn_mfma_f32_16x16x32_bf16(a2, bfrag(FG3 + 2), sacc, 0, 0, 0);
    sacc = __builtin_amdgcn_mfma_f32_16x16x32_bf16(a3, bfrag(FG3 + 3), sacc, 0, 0, 0);
  }
  f32x4 P0 = {0,0,0,0};
#pragma unroll
  for (int r = 0; r < 4; ++r) {
    float s = sacc[r];
    P0[r] = fmaf(cacc[0][r] * s, s, P0[r]);   // c0*s^2
    cacc[3][r] *= s;                          // c3 -> c3*s
  }

  __syncthreads();                 // all waves done reading XS (s)
  st_tile<48, 200>(XS, tid, bufV);
  __syncthreads();

  // ---------- G4: v[16x48] (3 tiles = components i) ----------
  f32x4 vacc[3];
  {
    short8 a[6];
#pragma unroll
    for (int kk = 0; kk < 6; ++kk) a[kk] = afrag(kk, 200);
#pragma unroll
    for (int i = 0; i < 3; ++i) {
      f32x4 acc = {0.f, 0.f, 0.f, 0.f};
#pragma unroll
      for (int kk = 0; kk < 6; ++kk)
        acc = __builtin_amdgcn_mfma_f32_16x16x32_bf16(a[kk], bfrag(FG4 + i*6 + kk), acc, 0, 0, 0);
      vacc[i] = acc;
    }
  }
  f32x4 Q0 = {0,0,0,0}, Q1 = {0,0,0,0}, Q2 = {0,0,0,0}, Q3 = {0,0,0,0}, Q4 = {0,0,0,0};
#pragma unroll
  for (int r = 0; r < 4; ++r) {
    float a = vacc[0][r], b = vacc[1][r], d = vacc[2][r];
    float nv = fmaf(a, a, fmaf(b, b, d * d));
    P0[r] = fmaf(cacc[1][r], nv, P0[r]);                     // c1*|v|^2
    float c4h = cacc[4][r];
    Q0[r] = fmaf(c4h, SQ2 * d * a, Q0[r]);
    Q1[r] = fmaf(c4h, SQ2 * a * b, Q1[r]);
    Q2[r] = fmaf(c4h, (2.f*b*b - d*d - a*a) * I6, Q2[r]);
    Q3[r] = fmaf(c4h, SQ2 * b * d, Q3[r]);
    Q4[r] = fmaf(c4h, (d*d - a*a) * I2, Q4[r]);
  }

  __syncthreads();                 // all waves done reading XS (v)
  stage_sync<40, 168>(xsp + 320, 480, baseRow, tid, XS);
  __syncthreads();

  // ---------- G5: t5[16x80] (5 tiles = components m) ----------
  f32x4 tacc[5];
  {
    short8 a[5];
#pragma unroll
    for (int kk = 0; kk < 5; ++kk) a[kk] = afrag(kk, 168);
#pragma unroll
    for (int m = 0; m < 5; ++m) {
      f32x4 acc = {0.f, 0.f, 0.f, 0.f};
#pragma unroll
      for (int kk = 0; kk < 5; ++kk)
        acc = __builtin_amdgcn_mfma_f32_16x16x32_bf16(a[kk], bfrag(FG5 + m*5 + kk), acc, 0, 0, 0);
      tacc[m] = acc;
    }
  }
#pragma unroll
  for (int r = 0; r < 4; ++r) {
    float q0 = tacc[0][r], q1 = tacc[1][r], q2 = tacc[2][r], q3 = tacc[3][r], q4 = tacc[4][r];
    float nt = fmaf(q0,q0, fmaf(q1,q1, fmaf(q2,q2, fmaf(q3,q3, q4*q4))));
    P0[r] = fmaf(cacc[2][r], nt, P0[r]);                     // c2*|t|^2
    float c3s = cacc[3][r];
    Q0[r] = fmaf(c3s, q0, Q0[r]);
    Q1[r] = fmaf(c3s, q1, Q1[r]);
    Q2[r] = fmaf(c3s, q2, Q2[r]);
    Q3[r] = fmaf(c3s, q3, Q3[r]);
    Q4[r] = fmaf(c3s, q4, Q4[r]);
    float d0 = -q2*I6 - q4*I2;
    float d1 =  2.f*q2*I6;
    float d2 = -q2*I6 + q4*I2;
    float a = q1*I2, b = q0*I2, cc = q3*I2;
    float A00 = fmaf(d0,d0, fmaf(a,a, b*b));
    float A11 = fmaf(a,a, fmaf(d1,d1, cc*cc));
    float A22 = fmaf(b,b, fmaf(cc,cc, d2*d2));
    float A01 = fmaf(a, d0 + d1, b*cc);
    float A02 = fmaf(b, d0 + d2, a*cc);
    float A12 = fmaf(cc, d1 + d2, a*b);
    float c5h = cacc[5][r];
    Q0[r] = fmaf(c5h, SQ2 * A02, Q0[r]);
    Q1[r] = fmaf(c5h, SQ2 * A01, Q1[r]);
    Q2[r] = fmaf(c5h, (2.f*A11 - A22 - A00) * I6, Q2[r]);
    Q3[r] = fmaf(c5h, SQ2 * A12, Q3[r]);
    Q4[r] = fmaf(c5h, (A22 - A00) * I2, Q4[r]);
  }

  // ---------- reduce over 16 h-lanes, segment accumulate ----------
  float* __restrict__ ACC = ws + ACC_OFF;
  int gmin = bidx[blk * 64];
#pragma unroll
  for (int r = 0; r < 4; ++r) {
    float z0 = P0[r], z1 = Q0[r], z2 = Q1[r], z3 = Q2[r], z4 = Q3[r], z5 = Q4[r];
#pragma unroll
    for (int d = 1; d < 16; d <<= 1) {
      z0 += __shfl_xor(z0, d); z1 += __shfl_xor(z1, d); z2 += __shfl_xor(z2, d);
      z3 += __shfl_xor(z3, d); z4 += __shfl_xor(z4, d); z5 += __shfl_xor(z5, d);
    }
    if (lo == 0) {
      int node = blk * 64 + w * 16 + hi * 4 + r;
      int g = bidx[node];
      int rel = g - gmin;
      if (rel < SPAN) {
        atomicAdd(&accL[rel*6 + 0], z0); atomicAdd(&accL[rel*6 + 1], z1);
        atomicAdd(&accL[rel*6 + 2], z2); atomicAdd(&accL[rel*6 + 3], z3);
        atomicAdd(&accL[rel*6 + 4], z4); atomicAdd(&accL[rel*6 + 5], z5);
      } else {
        atomicAdd(&ACC[g*6 + 0], z0); atomicAdd(&ACC[g*6 + 1], z1);
        atomicAdd(&ACC[g*6 + 2], z2); atomicAdd(&ACC[g*6 + 3], z3);
        atomicAdd(&ACC[g*6 + 4], z4); atomicAdd(&ACC[g*6 + 5], z5);
      }
    }
  }
  __syncthreads();
  for (int i = tid; i < SPAN * 6; i += TPB) {
    float val = accL[i];
    if (val != 0.f) atomicAdd(&ACC[gmin * 6 + i], val);
  }
}

__global__ __launch_bounds__(64) void finalize_kernel(
    const float* __restrict__ ws, float* __restrict__ out)
{
  int g = blockIdx.x * 64 + threadIdx.x;
  if (g >= G_GRP) return;
  const float I2 = 0.70710678118f, I3 = 0.57735026919f, I6 = 0.40824829046f;
  const float* A = ws + ACC_OFF + g * 6;
  float g0 = A[0], q0 = A[1], q1 = A[2], q2 = A[3], q3 = A[4], q4 = A[5];
  float M00 = g0*I3 - q2*I6 - q4*I2;
  float M11 = g0*I3 + 2.f*q2*I6;
  float M22 = g0*I3 - q2*I6 + q4*I2;
  float M01 = q1*I2, M02 = q0*I2, M12 = q3*I2;
  float* o = out + g * 9;
  o[0] = M22; o[1] = M02; o[2] = M12;
  o[3] = M02; o[4] = M00; o[5] = M01;
  o[6] = M12; o[7] = M01; o[8] = M11;
}

extern "C" void kernel_launch(void* const* d_in, const int* in_sizes, int n_in,
                              void* d_out, int out_size, void* d_ws, size_t ws_size,
                              hipStream_t stream)
{
  const float* xsc = (const float*)d_in[0];
  const float* xsp = (const float*)d_in[1];
  const int*   bidx = (const int*)d_in[3];
  const float* W0  = (const float*)d_in[4];
  const float* W1  = (const float*)d_in[5];
  const float* W2  = (const float*)d_in[6];
  const float* Wg1 = (const float*)d_in[7];
  const float* bg1 = (const float*)d_in[8];
  const float* Wg2 = (const float*)d_in[9];
  const float* bg2 = (const float*)d_in[10];
  const float* wp0 = (const float*)d_in[11];
  const float* wp2 = (const float*)d_in[12];
  float* ws = (float*)d_ws;

  repack_kernel<<<151, 256, 0, stream>>>(W0, W1, W2, Wg1, bg1, Wg2, bg2, wp0, wp2, ws);
  node_kernel<<<N_NODES / NPB, TPB, 0, stream>>>(xsc, xsp, bidx, ws);
  finalize_kernel<<<(G_GRP + 63) / 64, 64, 0, stream>>>(ws, (float*)d_out);
}